// Round 11
// baseline (474.740 us; speedup 1.0000x reference)
//
#include <hip/hip_runtime.h>
#include <hip/hip_cooperative_groups.h>
#include <cfloat>
#include <math.h>

namespace cg = cooperative_groups;

#define N_OBJ 8
#define N_PTS 2048
#define KNN   10
#define TOLC  0.01f
#define TPB   256
#define NW    4                 // waves per block = q-split factor
#define QC    (N_PTS / NW)      // 512 q's per wave
#define PC    64                // points per block (one wave-width)
#define NCHUNK (N_PTS / PC)     // 32 point-chunks per pair
#define NTILES (N_OBJ * (N_OBJ - 1) * NCHUNK)   // 1792

// ---- order-preserving float <-> uint for atomicMin on signed floats ----
__device__ __forceinline__ unsigned int enc_f(float f) {
    unsigned int u = __float_as_uint(f);
    return (u & 0x80000000u) ? ~u : (u | 0x80000000u);
}
__device__ __forceinline__ float dec_f(unsigned int e) {
    unsigned int u = (e & 0x80000000u) ? (e & 0x7fffffffu) : ~e;
    return __uint_as_float(u);
}

// Per-point transform, numerics verbatim from the verified k_transform
// (4x4 inverse redundantly in double). Writes P4=(x,y,z,|x|^2),
// N4=(nx,ny,nz,dot(n,x)), SD seed = enc(z).
__device__ __forceinline__ void transform_point(
        int gid, const float* __restrict__ pts, const float* __restrict__ T_est,
        const float* __restrict__ T_plane, float4* __restrict__ P4g,
        float4* __restrict__ N4g, unsigned int* __restrict__ SD) {
    int b = gid >> 11;

    double m[16];
#pragma unroll
    for (int i = 0; i < 16; i++) m[i] = (double)T_plane[i];
    double inv[16];
    inv[0]  =  m[5]*m[10]*m[15] - m[5]*m[11]*m[14] - m[9]*m[6]*m[15] + m[9]*m[7]*m[14] + m[13]*m[6]*m[11] - m[13]*m[7]*m[10];
    inv[4]  = -m[4]*m[10]*m[15] + m[4]*m[11]*m[14] + m[8]*m[6]*m[15] - m[8]*m[7]*m[14] - m[12]*m[6]*m[11] + m[12]*m[7]*m[10];
    inv[8]  =  m[4]*m[9]*m[15]  - m[4]*m[11]*m[13] - m[8]*m[5]*m[15] + m[8]*m[7]*m[13] + m[12]*m[5]*m[11] - m[12]*m[7]*m[9];
    inv[12] = -m[4]*m[9]*m[14]  + m[4]*m[10]*m[13] + m[8]*m[5]*m[14] - m[8]*m[6]*m[13] - m[12]*m[5]*m[10] + m[12]*m[6]*m[9];
    inv[1]  = -m[1]*m[10]*m[15] + m[1]*m[11]*m[14] + m[9]*m[2]*m[15] - m[9]*m[3]*m[14] - m[13]*m[2]*m[11] + m[13]*m[3]*m[10];
    inv[5]  =  m[0]*m[10]*m[15] - m[0]*m[11]*m[14] - m[8]*m[2]*m[15] + m[8]*m[3]*m[14] + m[12]*m[2]*m[11] - m[12]*m[3]*m[10];
    inv[9]  = -m[0]*m[9]*m[15]  + m[0]*m[11]*m[13] + m[8]*m[1]*m[15] - m[8]*m[3]*m[13] - m[12]*m[1]*m[11] + m[12]*m[3]*m[9];
    inv[13] =  m[0]*m[9]*m[14]  - m[0]*m[10]*m[13] - m[8]*m[1]*m[14] + m[8]*m[2]*m[13] + m[12]*m[1]*m[10] - m[12]*m[2]*m[9];
    inv[2]  =  m[1]*m[6]*m[15]  - m[1]*m[7]*m[14]  - m[5]*m[2]*m[15] + m[5]*m[3]*m[14] + m[13]*m[2]*m[7]  - m[13]*m[3]*m[6];
    inv[6]  = -m[0]*m[6]*m[15]  + m[0]*m[7]*m[14]  + m[4]*m[2]*m[15] - m[4]*m[3]*m[14] - m[12]*m[2]*m[7]  + m[12]*m[3]*m[6];
    inv[10] =  m[0]*m[5]*m[15]  - m[0]*m[7]*m[13]  - m[4]*m[1]*m[15] + m[4]*m[3]*m[13] + m[12]*m[1]*m[7]  - m[12]*m[3]*m[5];
    inv[14] = -m[0]*m[5]*m[14]  + m[0]*m[6]*m[13]  + m[4]*m[1]*m[14] - m[4]*m[2]*m[13] - m[12]*m[1]*m[6]  + m[12]*m[2]*m[5];
    inv[3]  = -m[1]*m[6]*m[11]  + m[1]*m[7]*m[10]  + m[5]*m[2]*m[11] - m[5]*m[3]*m[10] - m[9]*m[2]*m[7]   + m[9]*m[3]*m[6];
    inv[7]  =  m[0]*m[6]*m[11]  - m[0]*m[7]*m[10]  - m[4]*m[2]*m[11] + m[4]*m[3]*m[10] + m[8]*m[2]*m[7]   - m[8]*m[3]*m[6];
    inv[11] = -m[0]*m[5]*m[11]  + m[0]*m[7]*m[9]   + m[4]*m[1]*m[11] - m[4]*m[3]*m[9]  - m[8]*m[1]*m[7]   + m[8]*m[3]*m[5];
    inv[15] =  m[0]*m[5]*m[10]  - m[0]*m[6]*m[9]   - m[4]*m[1]*m[10] + m[4]*m[2]*m[9]  + m[8]*m[1]*m[6]   - m[8]*m[2]*m[5];
    double det  = m[0]*inv[0] + m[1]*inv[4] + m[2]*inv[8] + m[3]*inv[12];
    double rdet = 1.0 / det;

    const float* Te = T_est + b * 16;
    double M[12];
#pragma unroll
    for (int i = 0; i < 3; i++)
#pragma unroll
        for (int j = 0; j < 4; j++) {
            double s = 0.0;
#pragma unroll
            for (int kk = 0; kk < 4; kk++) s += inv[i*4+kk] * rdet * (double)Te[kk*4+j];
            M[i*4+j] = s;
        }

    const float* pp = pts + (size_t)gid * 6;
    double px = pp[0], py = pp[1], pz = pp[2];
    float nx = pp[3], ny = pp[4], nz = pp[5];
    float x = (float)(M[0]*px + M[1]*py + M[2]*pz  + M[3]);
    float y = (float)(M[4]*px + M[5]*py + M[6]*pz  + M[7]);
    float z = (float)(M[8]*px + M[9]*py + M[10]*pz + M[11]);
    float sq = fmaf(x, x, fmaf(y, y, z * z));
    float w  = fmaf(nx, x, fmaf(ny, y, nz * z));
    P4g[gid] = make_float4(x, y, z, sq);
    N4g[gid] = make_float4(nx, ny, nz, w);
    SD[gid]  = enc_f(z);   // seed min with the plane-distance term z
}

// One candidate: 22 VALU ops exactly, bit-identical op order to rounds 0-10.
// SGPR operand placement obeys the 1-SGPR-per-VALU rule.
#define QB(PX,PY,PZ,PW,NX,NY,NZ,NWW) \
  "v_mul_f32 %[t0], " PZ ", %[mz]\n" \
  "v_fma_f32 %[t0], %[my], " PY ", %[t0]\n" \
  "v_fma_f32 %[t0], %[mx], " PX ", %[t0]\n" \
  "v_add_f32 %[t0], " PW ", %[t0]\n" \
  "v_mul_f32 %[t1], " NZ ", %[gz]\n" \
  "v_fma_f32 %[t1], %[gy], " NY ", %[t1]\n" \
  "v_fma_f32 %[t1], %[gx], " NX ", %[t1]\n" \
  "v_add_f32 %[t1], " NWW ", %[t1]\n" \
  "v_and_b32 %[t0], -2, %[t0]\n" \
  "v_cmp_lt_f32 vcc, 0, %[t1]\n" \
  "v_cndmask_b32_e64 %[t1], 0, 1, vcc\n" \
  "v_or_b32 %[t0], %[t0], %[t1]\n" \
  "v_med3_f32 %[d9], %[d8], %[d9], %[t0]\n" \
  "v_med3_f32 %[d8], %[d7], %[d8], %[t0]\n" \
  "v_med3_f32 %[d7], %[d6], %[d7], %[t0]\n" \
  "v_med3_f32 %[d6], %[d5], %[d6], %[t0]\n" \
  "v_med3_f32 %[d5], %[d4], %[d5], %[t0]\n" \
  "v_med3_f32 %[d4], %[d3], %[d4], %[t0]\n" \
  "v_med3_f32 %[d3], %[d2], %[d3], %[t0]\n" \
  "v_med3_f32 %[d2], %[d1], %[d2], %[t0]\n" \
  "v_med3_f32 %[d1], %[d0], %[d1], %[t0]\n" \
  "v_min_f32 %[d0], %[d0], %[t0]\n"

// The proven r4 pair-scan core (k_pairs = 114.3us, best of 10 rounds):
// scalar-broadcast streams, double-banked SGPR buffers, full lgkmcnt(0)
// drains (SMEM completes OOO), pinned 22-VALU/q body. Operates on tile t.
__device__ __forceinline__ void pair_tile(
        int t, const float4* __restrict__ P4g, const float4* __restrict__ N4g,
        unsigned int* __restrict__ SD, float (*MRG)[PC][KNN + 1],
        int tid, int lane, int wu) {
    int pair = t >> 5;            // / NCHUNK
    int c64  = t & (NCHUNK - 1);
    int b  = pair / 7;
    int oi = pair % 7;
    int o  = oi + (oi >= b ? 1 : 0);
    int p    = c64 * PC + lane;

    float4 xp = P4g[b * N_PTS + p];          // per-lane point p (VMEM)
    float mx = -2.0f * xp.x, my = -2.0f * xp.y, mz = -2.0f * xp.z;
    float gx = -xp.x, gy = -xp.y, gz = -xp.z;

    const float4* Po = P4g + o * N_PTS + wu * QC;   // uniform stream bases
    const float4* No = N4g + o * N_PTS + wu * QC;
    unsigned long long ap = (unsigned long long)(uintptr_t)Po;
    unsigned long long an = (unsigned long long)(uintptr_t)No;
    unsigned int bpl = (unsigned int)ap, bph = (unsigned int)(ap >> 32);
    unsigned int bnl = (unsigned int)an, bnh = (unsigned int)(an >> 32);

    const float FMAXE = __uint_as_float(0x7F7FFFFEu);   // FLT_MAX, LSB clear
    float d0_ = FMAXE, d1_ = FMAXE, d2_ = FMAXE, d3_ = FMAXE, d4_ = FMAXE;
    float d5_ = FMAXE, d6_ = FMAXE, d7_ = FMAXE, d8_ = FMAXE, d9_ = FMAXE;
    float t0, t1;

    asm volatile(
        "s_mov_b32 s32, %[bpl]\n"
        "s_mov_b32 s33, %[bph]\n"
        "s_mov_b32 s34, %[bnl]\n"
        "s_mov_b32 s35, %[bnh]\n"
        "s_load_dwordx16 s[36:51], s[32:33], 0x0\n"
        "s_load_dwordx16 s[52:67], s[34:35], 0x0\n"
        "s_mov_b32 s30, 0\n"
        "Lkp%=:\n"
        "s_waitcnt lgkmcnt(0)\n"                         // bank A ready
        "s_load_dwordx16 s[68:83], s[32:33], 0x40\n"     // prefetch bank B
        "s_load_dwordx16 s[84:99], s[34:35], 0x40\n"
        QB("s36","s37","s38","s39","s52","s53","s54","s55")
        QB("s40","s41","s42","s43","s56","s57","s58","s59")
        QB("s44","s45","s46","s47","s60","s61","s62","s63")
        QB("s48","s49","s50","s51","s64","s65","s66","s67")
        "s_waitcnt lgkmcnt(0)\n"                         // bank B ready
        "s_load_dwordx16 s[36:51], s[32:33], 0x80\n"     // prefetch next A
        "s_load_dwordx16 s[52:67], s[34:35], 0x80\n"
        QB("s68","s69","s70","s71","s84","s85","s86","s87")
        QB("s72","s73","s74","s75","s88","s89","s90","s91")
        QB("s76","s77","s78","s79","s92","s93","s94","s95")
        QB("s80","s81","s82","s83","s96","s97","s98","s99")
        "s_add_u32 s32, s32, 0x80\n"
        "s_addc_u32 s33, s33, 0\n"
        "s_add_u32 s34, s34, 0x80\n"
        "s_addc_u32 s35, s35, 0\n"
        "s_add_u32 s30, s30, 1\n"
        "s_cmp_lt_u32 s30, 64\n"
        "s_cbranch_scc1 Lkp%=\n"
        "s_waitcnt lgkmcnt(0)\n"   // drain dangling prefetch before reg reuse
        : [d0]"+v"(d0_), [d1]"+v"(d1_), [d2]"+v"(d2_), [d3]"+v"(d3_),
          [d4]"+v"(d4_), [d5]"+v"(d5_), [d6]"+v"(d6_), [d7]"+v"(d7_),
          [d8]"+v"(d8_), [d9]"+v"(d9_), [t0]"=&v"(t0), [t1]"=&v"(t1)
        : [mx]"v"(mx), [my]"v"(my), [mz]"v"(mz),
          [gx]"v"(gx), [gy]"v"(gy), [gz]"v"(gz),
          [bpl]"s"(bpl), [bph]"s"(bph), [bnl]"s"(bnl), [bnh]"s"(bnh)
        : "s30","s31","s32","s33","s34","s35","s36","s37","s38","s39",
          "s40","s41","s42","s43","s44","s45","s46","s47","s48","s49",
          "s50","s51","s52","s53","s54","s55","s56","s57","s58","s59",
          "s60","s61","s62","s63","s64","s65","s66","s67","s68","s69",
          "s70","s71","s72","s73","s74","s75","s76","s77","s78","s79",
          "s80","s81","s82","s83","s84","s85","s86","s87","s88","s89",
          "s90","s91","s92","s93","s94","s95","s96","s97","s98","s99",
          "scc","vcc","memory");

    float td[KNN] = {d0_, d1_, d2_, d3_, d4_, d5_, d6_, d7_, d8_, d9_};

    if (wu > 0) {
#pragma unroll
        for (int j = 0; j < KNN; j++) MRG[wu][lane][j] = td[j];
    }
    __syncthreads();

    if (wu == 0) {
        // merge the 3 foreign partial top-10 lists into this wave's network
        // (top-k selection is partition-invariant on the value multiset)
#pragma unroll
        for (int ww = 1; ww < NW; ww++) {
#pragma unroll
            for (int j = 0; j < KNN; j++) {
                float cp = MRG[ww][lane][j];
#pragma unroll
                for (int tt = KNN - 1; tt >= 1; --tt)
                    td[tt] = __builtin_amdgcn_fmed3f(td[tt - 1], td[tt], cp);
                td[0] = fminf(td[0], cp);
            }
        }

        int cnt = 0;
#pragma unroll
        for (int j = 0; j < KNN; j++) cnt += (int)(__float_as_uint(td[j]) & 1u);
        float d2 = __uint_as_float(__float_as_uint(td[0]) & 0xFFFFFFFEu) + xp.w;
        float d0 = sqrtf(fmaxf(d2, 0.0f));
        if (cnt > 8) d0 = -d0;           // sum(insides) > k*0.8 = 8  ->  >= 9
        atomicMin(&SD[b * N_PTS + p], enc_f(d0));
    }
    __syncthreads();     // MRG reusable for the next tile (tile-stride case)
}

// SINGLE fused cooperative kernel: transform -> grid.sync -> pairs (r4 core,
// tile-stride) -> grid.sync -> final decode. Removes 2 of 3 dispatches
// (r4: total 168us, k_pairs 114us -> ~54us was transform+final+launch gaps).
// __launch_bounds__(256,7): VGPR<=73, SGPR 112 -> 7 waves/SIMD -> 7 blocks/CU
// -> 1792 blocks co-resident (phase-2 occupancy identical to r4's launch).
// Phase-1 doubles spill under the bound — executed by 1 wave/block (<=10
// points each via i = tid*gridDim.x + bx), latency ~2-4us, fully parallel.
__global__ void __launch_bounds__(TPB, 7) k_fused(
        const float* __restrict__ pts, const float* __restrict__ T_est,
        const float* __restrict__ T_plane, float4* __restrict__ P4g,
        float4* __restrict__ N4g, unsigned int* __restrict__ SD,
        float* __restrict__ out) {
    __shared__ float MRG[NW][PC][KNN + 1];   // stride 11: conflict-free
    cg::grid_group grid = cg::this_grid();

    int tid  = threadIdx.x;
    int bx   = blockIdx.x;
    int lane = tid & 63;
    int wu   = __builtin_amdgcn_readfirstlane(tid >> 6);

    // ---- phase 1: transform (spread: lowest ~10 lanes of wave 0 per block)
    {
        int i = tid * gridDim.x + bx;
        if (i < N_OBJ * N_PTS)
            transform_point(i, pts, T_est, T_plane, P4g, N4g, SD);
    }
    __threadfence();
    grid.sync();

    // ---- phase 2: pair scan, tile-stride (1 tile/block at full residency)
    for (int t = bx; t < NTILES; t += gridDim.x)
        pair_tile(t, P4g, N4g, SD, MRG, tid, lane, wu);

    __threadfence();
    grid.sync();

    // ---- phase 3: decode and emit both outputs
    {
        int gid = bx * TPB + tid;
        if (gid < N_OBJ * N_PTS) {
            float sd = dec_f(SD[gid]);
            out[gid] = sd;
            out[N_OBJ * N_PTS + gid] = (sd < -TOLC) ? 1.0f : 0.0f;
        }
    }
}

// ---------- legacy 3-kernel fallback (verbatim r4 behavior) ----------
__global__ void k_transform(const float* __restrict__ pts,
                            const float* __restrict__ T_est,
                            const float* __restrict__ T_plane,
                            float4* __restrict__ P4g,
                            float4* __restrict__ N4g,
                            unsigned int* __restrict__ SD) {
    int gid = blockIdx.x * blockDim.x + threadIdx.x;
    if (gid >= N_OBJ * N_PTS) return;
    transform_point(gid, pts, T_est, T_plane, P4g, N4g, SD);
}

__global__ void __launch_bounds__(TPB, 7) k_pairs(const float4* __restrict__ P4g,
                                                  const float4* __restrict__ N4g,
                                                  unsigned int* __restrict__ SD) {
    __shared__ float MRG[NW][PC][KNN + 1];
    int tid  = threadIdx.x;
    int lane = tid & 63;
    int wu   = __builtin_amdgcn_readfirstlane(tid >> 6);
    pair_tile(blockIdx.x, P4g, N4g, SD, MRG, tid, lane, wu);
}

__global__ void k_final(const unsigned int* __restrict__ SD,
                        float* __restrict__ out) {
    int gid = blockIdx.x * blockDim.x + threadIdx.x;
    if (gid >= N_OBJ * N_PTS) return;
    float sd = dec_f(SD[gid]);
    out[gid] = sd;
    out[N_OBJ * N_PTS + gid] = (sd < -TOLC) ? 1.0f : 0.0f;
}

extern "C" void kernel_launch(void* const* d_in, const int* in_sizes, int n_in,
                              void* d_out, int out_size, void* d_ws, size_t ws_size,
                              hipStream_t stream) {
    const float* pts     = (const float*)d_in[0];   // (8,2048,6)
    const float* T_est   = (const float*)d_in[1];   // (8,4,4)
    const float* T_plane = (const float*)d_in[2];   // (4,4)
    // d_in[3] is k == 10, hardcoded as KNN

    // workspace layout: P4 (256KB) | N4 (256KB) | SD (64KB)
    float4*       P4 = (float4*)d_ws;
    float4*       N4 = P4 + N_OBJ * N_PTS;
    unsigned int* SD = (unsigned int*)(N4 + N_OBJ * N_PTS);
    float*        out = (float*)d_out;

    // one-time co-residency query (host-side, capture-safe: no stream ops)
    static int nblk = -2;          // -2 = not queried; -1 = fallback
    if (nblk == -2) {
        int dev = 0, coop = 0, ncu = 0, maxB = 0;
        (void)hipGetDevice(&dev);
        (void)hipDeviceGetAttribute(&coop, hipDeviceAttributeCooperativeLaunch, dev);
        (void)hipDeviceGetAttribute(&ncu, hipDeviceAttributeMultiprocessorCount, dev);
        hipError_t oe = hipOccupancyMaxActiveBlocksPerMultiprocessor(
                            &maxB, (const void*)k_fused, TPB, 0);
        if (coop && oe == hipSuccess && maxB > 0 && ncu > 0) {
            long cap = (long)maxB * (long)ncu;
            nblk = (int)(cap < (long)NTILES ? cap : (long)NTILES);
        } else {
            nblk = -1;
        }
    }

    if (nblk > 0) {
        void* args[] = {(void*)&pts, (void*)&T_est, (void*)&T_plane,
                        (void*)&P4, (void*)&N4, (void*)&SD, (void*)&out};
        hipError_t err = hipLaunchCooperativeKernel(
            (const void*)k_fused, dim3(nblk), dim3(TPB), args, 0, stream);
        if (err == hipSuccess) return;
        (void)hipGetLastError();   // clear error state; fall back permanently
        nblk = -1;
    }

    // fallback: proven 3-kernel path (r4 = 168us total)
    k_transform<<<(N_OBJ * N_PTS) / TPB, TPB, 0, stream>>>(pts, T_est, T_plane, P4, N4, SD);
    k_pairs<<<NTILES, TPB, 0, stream>>>(P4, N4, SD);
    k_final<<<(N_OBJ * N_PTS) / TPB, TPB, 0, stream>>>(SD, out);
}

// Round 12
// 167.579 us; speedup vs baseline: 2.8329x; 2.8329x over previous
//
#include <hip/hip_runtime.h>
#include <cfloat>
#include <math.h>

#define N_OBJ 8
#define N_PTS 2048
#define KNN   10
#define TOLC  0.01f
#define TPB   256
#define NW    4                 // waves per block = q-split factor
#define QC    (N_PTS / NW)      // 512 q's per wave
#define PC    64                // points per block (one wave-width)
#define NCHUNK (N_PTS / PC)     // 8 tiles per pair -> 32 point-chunks

// ---- order-preserving float <-> uint for atomicMin on signed floats ----
__device__ __forceinline__ unsigned int enc_f(float f) {
    unsigned int u = __float_as_uint(f);
    return (u & 0x80000000u) ? ~u : (u | 0x80000000u);
}
__device__ __forceinline__ float dec_f(unsigned int e) {
    unsigned int u = (e & 0x80000000u) ? (e & 0x7fffffffu) : ~e;
    return __uint_as_float(u);
}

// Kernel 1: per-point transform (4x4 inverse redundantly in double — closer
// to the numpy reference than fp32 adjugate; trivial cost at 64 waves).
// Writes P4=(x,y,z,|x|^2), N4=(nx,ny,nz,dot(n,x)), SD seed = enc(z).
__global__ void k_transform(const float* __restrict__ pts,
                            const float* __restrict__ T_est,
                            const float* __restrict__ T_plane,
                            float4* __restrict__ P4g,
                            float4* __restrict__ N4g,
                            unsigned int* __restrict__ SD) {
    int gid = blockIdx.x * blockDim.x + threadIdx.x;
    if (gid >= N_OBJ * N_PTS) return;
    int b = gid >> 11;

    double m[16];
#pragma unroll
    for (int i = 0; i < 16; i++) m[i] = (double)T_plane[i];
    double inv[16];
    inv[0]  =  m[5]*m[10]*m[15] - m[5]*m[11]*m[14] - m[9]*m[6]*m[15] + m[9]*m[7]*m[14] + m[13]*m[6]*m[11] - m[13]*m[7]*m[10];
    inv[4]  = -m[4]*m[10]*m[15] + m[4]*m[11]*m[14] + m[8]*m[6]*m[15] - m[8]*m[7]*m[14] - m[12]*m[6]*m[11] + m[12]*m[7]*m[10];
    inv[8]  =  m[4]*m[9]*m[15]  - m[4]*m[11]*m[13] - m[8]*m[5]*m[15] + m[8]*m[7]*m[13] + m[12]*m[5]*m[11] - m[12]*m[7]*m[9];
    inv[12] = -m[4]*m[9]*m[14]  + m[4]*m[10]*m[13] + m[8]*m[5]*m[14] - m[8]*m[6]*m[13] - m[12]*m[5]*m[10] + m[12]*m[6]*m[9];
    inv[1]  = -m[1]*m[10]*m[15] + m[1]*m[11]*m[14] + m[9]*m[2]*m[15] - m[9]*m[3]*m[14] - m[13]*m[2]*m[11] + m[13]*m[3]*m[10];
    inv[5]  =  m[0]*m[10]*m[15] - m[0]*m[11]*m[14] - m[8]*m[2]*m[15] + m[8]*m[3]*m[14] + m[12]*m[2]*m[11] - m[12]*m[3]*m[10];
    inv[9]  = -m[0]*m[9]*m[15]  + m[0]*m[11]*m[13] + m[8]*m[1]*m[15] - m[8]*m[3]*m[13] - m[12]*m[1]*m[11] + m[12]*m[3]*m[9];
    inv[13] =  m[0]*m[9]*m[14]  - m[0]*m[10]*m[13] - m[8]*m[1]*m[14] + m[8]*m[2]*m[13] + m[12]*m[1]*m[10] - m[12]*m[2]*m[9];
    inv[2]  =  m[1]*m[6]*m[15]  - m[1]*m[7]*m[14]  - m[5]*m[2]*m[15] + m[5]*m[3]*m[14] + m[13]*m[2]*m[7]  - m[13]*m[3]*m[6];
    inv[6]  = -m[0]*m[6]*m[15]  + m[0]*m[7]*m[14]  + m[4]*m[2]*m[15] - m[4]*m[3]*m[14] - m[12]*m[2]*m[7]  + m[12]*m[3]*m[6];
    inv[10] =  m[0]*m[5]*m[15]  - m[0]*m[7]*m[13]  - m[4]*m[1]*m[15] + m[4]*m[3]*m[13] + m[12]*m[1]*m[7]  - m[12]*m[3]*m[5];
    inv[14] = -m[0]*m[5]*m[14]  + m[0]*m[6]*m[13]  + m[4]*m[1]*m[14] - m[4]*m[2]*m[13] - m[12]*m[1]*m[6]  + m[12]*m[2]*m[5];
    inv[3]  = -m[1]*m[6]*m[11]  + m[1]*m[7]*m[10]  + m[5]*m[2]*m[11] - m[5]*m[3]*m[10] - m[9]*m[2]*m[7]   + m[9]*m[3]*m[6];
    inv[7]  =  m[0]*m[6]*m[11]  - m[0]*m[7]*m[10]  - m[4]*m[2]*m[11] + m[4]*m[3]*m[10] + m[8]*m[2]*m[7]   - m[8]*m[3]*m[6];
    inv[11] = -m[0]*m[5]*m[11]  + m[0]*m[7]*m[9]   + m[4]*m[1]*m[11] - m[4]*m[3]*m[9]  - m[8]*m[1]*m[7]   + m[8]*m[3]*m[5];
    inv[15] =  m[0]*m[5]*m[10]  - m[0]*m[6]*m[9]   - m[4]*m[1]*m[10] + m[4]*m[2]*m[9]  + m[8]*m[1]*m[6]   - m[8]*m[2]*m[5];
    double det  = m[0]*inv[0] + m[1]*inv[4] + m[2]*inv[8] + m[3]*inv[12];
    double rdet = 1.0 / det;

    const float* Te = T_est + b * 16;
    double M[12];
#pragma unroll
    for (int i = 0; i < 3; i++)
#pragma unroll
        for (int j = 0; j < 4; j++) {
            double s = 0.0;
#pragma unroll
            for (int kk = 0; kk < 4; kk++) s += inv[i*4+kk] * rdet * (double)Te[kk*4+j];
            M[i*4+j] = s;
        }

    const float* pp = pts + (size_t)gid * 6;
    double px = pp[0], py = pp[1], pz = pp[2];
    float nx = pp[3], ny = pp[4], nz = pp[5];
    float x = (float)(M[0]*px + M[1]*py + M[2]*pz  + M[3]);
    float y = (float)(M[4]*px + M[5]*py + M[6]*pz  + M[7]);
    float z = (float)(M[8]*px + M[9]*py + M[10]*pz + M[11]);
    float sq = fmaf(x, x, fmaf(y, y, z * z));
    float w  = fmaf(nx, x, fmaf(ny, y, nz * z));
    P4g[gid] = make_float4(x, y, z, sq);
    N4g[gid] = make_float4(nx, ny, nz, w);
    SD[gid]  = enc_f(z);   // seed min with the plane-distance term z
}

// One candidate: 22 VALU ops exactly. Same op order as the C version ->
// bit-identical results. SGPR operand placement obeys the 1-SGPR-per-VALU
// rule (SGPR in src0 for VOP2, src1 for VOP3 fma).
#define QB(PX,PY,PZ,PW,NX,NY,NZ,NWW) \
  "v_mul_f32 %[t0], " PZ ", %[mz]\n" \
  "v_fma_f32 %[t0], %[my], " PY ", %[t0]\n" \
  "v_fma_f32 %[t0], %[mx], " PX ", %[t0]\n" \
  "v_add_f32 %[t0], " PW ", %[t0]\n" \
  "v_mul_f32 %[t1], " NZ ", %[gz]\n" \
  "v_fma_f32 %[t1], %[gy], " NY ", %[t1]\n" \
  "v_fma_f32 %[t1], %[gx], " NX ", %[t1]\n" \
  "v_add_f32 %[t1], " NWW ", %[t1]\n" \
  "v_and_b32 %[t0], -2, %[t0]\n" \
  "v_cmp_lt_f32 vcc, 0, %[t1]\n" \
  "v_cndmask_b32_e64 %[t1], 0, 1, vcc\n" \
  "v_or_b32 %[t0], %[t0], %[t1]\n" \
  "v_med3_f32 %[d9], %[d8], %[d9], %[t0]\n" \
  "v_med3_f32 %[d8], %[d7], %[d8], %[t0]\n" \
  "v_med3_f32 %[d7], %[d6], %[d7], %[t0]\n" \
  "v_med3_f32 %[d6], %[d5], %[d6], %[t0]\n" \
  "v_med3_f32 %[d5], %[d4], %[d5], %[t0]\n" \
  "v_med3_f32 %[d4], %[d3], %[d4], %[t0]\n" \
  "v_med3_f32 %[d3], %[d2], %[d3], %[t0]\n" \
  "v_med3_f32 %[d2], %[d1], %[d2], %[t0]\n" \
  "v_med3_f32 %[d1], %[d0], %[d1], %[t0]\n" \
  "v_min_f32 %[d0], %[d0], %[t0]\n"

// Kernel 2 (r4, session-best k_pairs = 114.3us): scalar-broadcast streams,
// 4-wave q-split, LDS merge; the entire QC-scan is ONE inline-asm loop
// pinning the body at 22 VALU/q.
//   - double-banked SGPR buffers: bank A s[36:67], bank B s[68:99]
//     (P 16 + N 16 dwords each = 4 q's per bank), bases s[32:35], ctr s30
//   - s_load_dwordx16 pairs issued one group ahead; lgkmcnt(0) only (SMEM
//     returns out-of-order -> partial lgkm waits are unsafe); latency hidden
//     by own compute (~176 cy per 4-q group) + 28 waves/CU
//   - last prefetch reads <=64B past the wave's window: stays inside the
//     P4|N4|SD workspace for every (o,wu) incl. the worst case o=7,wu=3.
__global__ void __launch_bounds__(TPB, 8) k_pairs(const float4* __restrict__ P4g,
                                                  const float4* __restrict__ N4g,
                                                  unsigned int* __restrict__ SD) {
    // stride 11 floats: 11 coprime 32 -> 2 lanes/bank, conflict-free
    __shared__ float MRG[NW][PC][KNN + 1];

    int bx   = blockIdx.x;
    int pair = bx >> 5;            // / NCHUNK
    int c64  = bx & (NCHUNK - 1);
    int b  = pair / 7;
    int oi = pair % 7;
    int o  = oi + (oi >= b ? 1 : 0);
    int tid  = threadIdx.x;
    int lane = tid & 63;
    // wave id as a PROVABLY-uniform (SGPR) value
    int wu   = __builtin_amdgcn_readfirstlane(tid >> 6);
    int p    = c64 * PC + lane;

    float4 xp = P4g[b * N_PTS + p];          // per-lane point p (VMEM)
    float mx = -2.0f * xp.x, my = -2.0f * xp.y, mz = -2.0f * xp.z;
    float gx = -xp.x, gy = -xp.y, gz = -xp.z;

    const float4* Po = P4g + o * N_PTS + wu * QC;   // uniform stream bases
    const float4* No = N4g + o * N_PTS + wu * QC;
    unsigned long long ap = (unsigned long long)(uintptr_t)Po;
    unsigned long long an = (unsigned long long)(uintptr_t)No;
    unsigned int bpl = (unsigned int)ap, bph = (unsigned int)(ap >> 32);
    unsigned int bnl = (unsigned int)an, bnh = (unsigned int)(an >> 32);

    const float FMAXE = __uint_as_float(0x7F7FFFFEu);   // FLT_MAX, LSB clear
    float d0_ = FMAXE, d1_ = FMAXE, d2_ = FMAXE, d3_ = FMAXE, d4_ = FMAXE;
    float d5_ = FMAXE, d6_ = FMAXE, d7_ = FMAXE, d8_ = FMAXE, d9_ = FMAXE;
    float t0, t1;

    asm volatile(
        "s_mov_b32 s32, %[bpl]\n"
        "s_mov_b32 s33, %[bph]\n"
        "s_mov_b32 s34, %[bnl]\n"
        "s_mov_b32 s35, %[bnh]\n"
        "s_load_dwordx16 s[36:51], s[32:33], 0x0\n"
        "s_load_dwordx16 s[52:67], s[34:35], 0x0\n"
        "s_mov_b32 s30, 0\n"
        "Lkp%=:\n"
        "s_waitcnt lgkmcnt(0)\n"                         // bank A ready
        "s_load_dwordx16 s[68:83], s[32:33], 0x40\n"     // prefetch bank B
        "s_load_dwordx16 s[84:99], s[34:35], 0x40\n"
        QB("s36","s37","s38","s39","s52","s53","s54","s55")
        QB("s40","s41","s42","s43","s56","s57","s58","s59")
        QB("s44","s45","s46","s47","s60","s61","s62","s63")
        QB("s48","s49","s50","s51","s64","s65","s66","s67")
        "s_waitcnt lgkmcnt(0)\n"                         // bank B ready
        "s_load_dwordx16 s[36:51], s[32:33], 0x80\n"     // prefetch next A
        "s_load_dwordx16 s[52:67], s[34:35], 0x80\n"
        QB("s68","s69","s70","s71","s84","s85","s86","s87")
        QB("s72","s73","s74","s75","s88","s89","s90","s91")
        QB("s76","s77","s78","s79","s92","s93","s94","s95")
        QB("s80","s81","s82","s83","s96","s97","s98","s99")
        "s_add_u32 s32, s32, 0x80\n"
        "s_addc_u32 s33, s33, 0\n"
        "s_add_u32 s34, s34, 0x80\n"
        "s_addc_u32 s35, s35, 0\n"
        "s_add_u32 s30, s30, 1\n"
        "s_cmp_lt_u32 s30, 64\n"
        "s_cbranch_scc1 Lkp%=\n"
        "s_waitcnt lgkmcnt(0)\n"   // drain dangling prefetch before reg reuse
        : [d0]"+v"(d0_), [d1]"+v"(d1_), [d2]"+v"(d2_), [d3]"+v"(d3_),
          [d4]"+v"(d4_), [d5]"+v"(d5_), [d6]"+v"(d6_), [d7]"+v"(d7_),
          [d8]"+v"(d8_), [d9]"+v"(d9_), [t0]"=&v"(t0), [t1]"=&v"(t1)
        : [mx]"v"(mx), [my]"v"(my), [mz]"v"(mz),
          [gx]"v"(gx), [gy]"v"(gy), [gz]"v"(gz),
          [bpl]"s"(bpl), [bph]"s"(bph), [bnl]"s"(bnl), [bnh]"s"(bnh)
        : "s30","s31","s32","s33","s34","s35","s36","s37","s38","s39",
          "s40","s41","s42","s43","s44","s45","s46","s47","s48","s49",
          "s50","s51","s52","s53","s54","s55","s56","s57","s58","s59",
          "s60","s61","s62","s63","s64","s65","s66","s67","s68","s69",
          "s70","s71","s72","s73","s74","s75","s76","s77","s78","s79",
          "s80","s81","s82","s83","s84","s85","s86","s87","s88","s89",
          "s90","s91","s92","s93","s94","s95","s96","s97","s98","s99",
          "scc","vcc","memory");

    float td[KNN] = {d0_, d1_, d2_, d3_, d4_, d5_, d6_, d7_, d8_, d9_};

    if (wu > 0) {
#pragma unroll
        for (int j = 0; j < KNN; j++) MRG[wu][lane][j] = td[j];
    }
    __syncthreads();

    if (wu == 0) {
        // merge the 3 foreign partial top-10 lists into this wave's network
        // (top-k selection is partition-invariant on the value multiset)
#pragma unroll
        for (int ww = 1; ww < NW; ww++) {
#pragma unroll
            for (int j = 0; j < KNN; j++) {
                float cp = MRG[ww][lane][j];
#pragma unroll
                for (int t = KNN - 1; t >= 1; --t)
                    td[t] = __builtin_amdgcn_fmed3f(td[t - 1], td[t], cp);
                td[0] = fminf(td[0], cp);
            }
        }

        int cnt = 0;
#pragma unroll
        for (int j = 0; j < KNN; j++) cnt += (int)(__float_as_uint(td[j]) & 1u);
        float d2 = __uint_as_float(__float_as_uint(td[0]) & 0xFFFFFFFEu) + xp.w;
        float d0 = sqrtf(fmaxf(d2, 0.0f));
        if (cnt > 8) d0 = -d0;           // sum(insides) > k*0.8 = 8  ->  >= 9
        atomicMin(&SD[b * N_PTS + p], enc_f(d0));
    }
}

// Kernel 3: decode and emit both outputs (signed_distance, then intersects
// as 0.0/1.0 floats).
__global__ void k_final(const unsigned int* __restrict__ SD,
                        float* __restrict__ out) {
    int gid = blockIdx.x * blockDim.x + threadIdx.x;
    if (gid >= N_OBJ * N_PTS) return;
    float sd = dec_f(SD[gid]);
    out[gid] = sd;
    out[N_OBJ * N_PTS + gid] = (sd < -TOLC) ? 1.0f : 0.0f;
}

extern "C" void kernel_launch(void* const* d_in, const int* in_sizes, int n_in,
                              void* d_out, int out_size, void* d_ws, size_t ws_size,
                              hipStream_t stream) {
    const float* pts     = (const float*)d_in[0];   // (8,2048,6)
    const float* T_est   = (const float*)d_in[1];   // (8,4,4)
    const float* T_plane = (const float*)d_in[2];   // (4,4)
    // d_in[3] is k == 10, hardcoded as KNN

    // workspace layout: P4 (256KB) | N4 (256KB) | SD (64KB)
    float4*       P4 = (float4*)d_ws;
    float4*       N4 = P4 + N_OBJ * N_PTS;
    unsigned int* SD = (unsigned int*)(N4 + N_OBJ * N_PTS);

    float* out = (float*)d_out;

    k_transform<<<(N_OBJ * N_PTS) / 256, 256, 0, stream>>>(pts, T_est, T_plane, P4, N4, SD);
    k_pairs<<<N_OBJ * (N_OBJ - 1) * NCHUNK, TPB, 0, stream>>>(P4, N4, SD);
    k_final<<<(N_OBJ * N_PTS) / 256, 256, 0, stream>>>(SD, out);
}